// Round 6
// baseline (250.243 us; speedup 1.0000x reference)
//
#include <hip/hip_runtime.h>
#include <hip/hip_bf16.h>
#include <stdint.h>
#include <math.h>

#define BB 4
#define NN 2048
#define NFEAT 256
#define NHID 64
#define NHEADS 4
#define NCLASS 32
#define KK1 256
#define ALPHA 0.2f
#define LOG2E 1.4426950408889634f

typedef _Float16 f16x8 __attribute__((ext_vector_type(8)));
typedef _Float16 f16x4 __attribute__((ext_vector_type(4)));
typedef _Float16 h16x2 __attribute__((ext_vector_type(2)));
typedef float f32x4 __attribute__((ext_vector_type(4)));

__device__ __forceinline__ f16x8 ld8(const _Float16* p){
  f16x8 r;
  *(f16x4*)&r = *(const f16x4*)p;
  *((f16x4*)&r + 1) = *(const f16x4*)(p + 4);
  return r;
}

__device__ __forceinline__ h16x2 pk2(float a, float b){
  auto v = __builtin_amdgcn_cvt_pkrtz(a, b);   // __fp16 x2
  h16x2 r;
  __builtin_memcpy(&r, &v, sizeof(r));
  return r;
}

// ---------------- K0: pack adj int32 -> bitmask + per-row count ---------
__global__ void __launch_bounds__(256) pack_adj(const int* __restrict__ adj,
                                                unsigned long long* __restrict__ bits,
                                                int* __restrict__ cnt){
  __shared__ int csum[4];
  int row = blockIdx.x;                       // b*N + i
  const int* arow = adj + (size_t)row * NN;
  int lane = threadIdx.x & 63, wv = threadIdx.x >> 6;
  int c = 0;
  #pragma unroll
  for (int it=0; it<NN/256; ++it){
    int j = it*256 + threadIdx.x;
    unsigned long long m = __ballot(arow[j] > 0);
    if (lane==0){ bits[(size_t)row*(NN/64) + it*4 + wv] = m; c += __popcll(m); }
  }
  if (lane==0) csum[wv] = c;
  __syncthreads();
  if (threadIdx.x==0) cnt[row] = csum[0]+csum[1]+csum[2]+csum[3];
}

// ---------------- K1: WhT(f16) = (x @ W)^T per head, f1l/f2l (log2e) ----
__global__ void __launch_bounds__(256) wh_proj2(const float* __restrict__ x,
        const float* __restrict__ W, const float* __restrict__ a1, const float* __restrict__ a2,
        _Float16* __restrict__ whT, float* __restrict__ f1l, float* __restrict__ f2l){
  __shared__ __align__(16) float xs[64*65];
  __shared__ float red1[4][64];
  __shared__ float red2[4][64];
  int bh = blockIdx.x >> 5;
  int i0 = (blockIdx.x & 31) * 64;
  int b = bh >> 2, h = bh & 3;
  int tid = threadIdx.x;
  int lane = tid & 63;
  int dbase = __builtin_amdgcn_readfirstlane(tid >> 6) * 16;
  float acc[16];
  #pragma unroll
  for (int dd=0; dd<16; ++dd) acc[dd] = 0.f;
  for (int kc=0; kc<4; ++kc){
    int kb = kc*64;
    __syncthreads();
    #pragma unroll
    for (int t=0; t<4; ++t){
      int row = t*16 + (tid>>4);
      int f4 = (tid&15)*4;
      float4 v = *(const float4*)(x + ((size_t)(b*NN + i0 + row))*NFEAT + kb + f4);
      xs[row*65 + f4 + 0] = v.x;
      xs[row*65 + f4 + 1] = v.y;
      xs[row*65 + f4 + 2] = v.z;
      xs[row*65 + f4 + 3] = v.w;
    }
    __syncthreads();
    const float* Wb = W + (size_t)h*NFEAT*NHID + (size_t)kb*NHID + dbase;
    #pragma unroll 4
    for (int f=0; f<64; ++f){
      float xv = xs[lane*65 + f];
      const float* wr = Wb + f*NHID;
      #pragma unroll
      for (int dd=0; dd<16; ++dd) acc[dd] = fmaf(xv, wr[dd], acc[dd]);
    }
  }
  float p1 = 0.f, p2 = 0.f;
  #pragma unroll
  for (int dd=0; dd<16; ++dd){
    int d = dbase + dd;
    whT[((size_t)bh*NHID + d)*NN + i0 + lane] = (_Float16)acc[dd];
    p1 = fmaf(acc[dd], a1[h*NHID + d], p1);
    p2 = fmaf(acc[dd], a2[h*NHID + d], p2);
  }
  int wv = tid >> 6;
  red1[wv][lane] = p1;
  red2[wv][lane] = p2;
  __syncthreads();
  if (tid < 64){
    float s1 = red1[0][tid]+red1[1][tid]+red1[2][tid]+red1[3][tid];
    float s2 = red2[0][tid]+red2[1][tid]+red2[2][tid]+red2[3][tid];
    f1l[(size_t)bh*NN + i0 + tid] = s1 * LOG2E;
    f2l[(size_t)bh*NN + i0 + tid] = s2 * LOG2E;
  }
}

// ---------- K2: h1 = elu(softmax(e) @ Wh), barrier-free wave-K-split ----
// grid = bh(16) x tile(64); block 256 = 4 waves. Wave w owns j in
// [w*512, w*512+512). A-fragments (weights) computed per-lane directly in
// MFMA A-layout: lane(q,col) -> rows i0+col / i0+16+col, k=q*8+jj.
// B-fragments read straight from global whT (f16 [bh][d][j], 16B/lane).
// No main-loop barriers; one epilogue barrier for cross-wave C/l reduce.
__global__ void __launch_bounds__(256) attn_l1(
        const unsigned long long* __restrict__ bits,
        const _Float16* __restrict__ whT,
        const float* __restrict__ f1l, const float* __restrict__ f2l,
        const int* __restrict__ cnt_in,
        float* __restrict__ dst){
  const int CP = 68;                               // f32 pitch, 2-way banks (free)
  __shared__ __align__(16) float cred[4][32*CP];   // 4 x 8.5 KB
  __shared__ float lred[4][32];
  int tile = blockIdx.x & 63;
  int bh = blockIdx.x >> 6;
  int b = bh >> 2, h = bh & 3;
  int i0 = tile*32;
  int tid = threadIdx.x;
  int lane = tid & 63, wv = tid >> 6;
  int q = lane >> 4, col = lane & 15;
  int r0 = i0 + col, r1 = i0 + 16 + col;
  float f1a = f1l[(size_t)bh*NN + r0];
  float f1b = f1l[(size_t)bh*NN + r1];
  bool cza = (cnt_in[b*NN + r0] == 0);
  bool czb = (cnt_in[b*NN + r1] == 0);
  const unsigned int* ma = (const unsigned int*)(bits + ((size_t)(b*NN + r0))*(NN/64));
  const unsigned int* mb = (const unsigned int*)(bits + ((size_t)(b*NN + r1))*(NN/64));
  const float* f2p = f2l + (size_t)bh*NN;
  const _Float16* whg = whT + (size_t)bh*NHID*NN;
  float la = 0.f, lb = 0.f;
  f32x4 acc[2][4];
  #pragma unroll
  for (int mt=0; mt<2; ++mt)
    #pragma unroll
    for (int nt=0; nt<4; ++nt) acc[mt][nt] = f32x4{0.f,0.f,0.f,0.f};

  #pragma unroll 2
  for (int ks=0; ks<16; ++ks){
    int jb = wv*512 + ks*32;
    int j8 = jb + q*8;
    unsigned int mwa = ma[jb>>5];
    unsigned int mwb = mb[jb>>5];
    float4 fa  = *(const float4*)(f2p + j8);
    float4 fbv = *(const float4*)(f2p + j8 + 4);
    float fvv[8] = {fa.x,fa.y,fa.z,fa.w, fbv.x,fbv.y,fbv.z,fbv.w};
    union { f16x8 v; h16x2 h[4]; } ua, ub;
    #pragma unroll
    for (int p=0; p<4; ++p){
      unsigned sh = q*8 + 2*p;
      float s00 = f1a + fvv[2*p],   s01 = f1a + fvv[2*p+1];
      float s10 = f1b + fvv[2*p],   s11 = f1b + fvv[2*p+1];
      s00 = ((mwa>>sh)&1u)     ? s00 : -1e5f;
      s01 = ((mwa>>(sh+1))&1u) ? s01 : -1e5f;
      s10 = ((mwb>>sh)&1u)     ? s10 : -1e5f;
      s11 = ((mwb>>(sh+1))&1u) ? s11 : -1e5f;
      float w00 = __builtin_amdgcn_exp2f(fmaxf(s00, ALPHA*s00));
      float w01 = __builtin_amdgcn_exp2f(fmaxf(s01, ALPHA*s01));
      float w10 = __builtin_amdgcn_exp2f(fmaxf(s10, ALPHA*s10));
      float w11 = __builtin_amdgcn_exp2f(fmaxf(s11, ALPHA*s11));
      w00 = cza ? 1.f : w00;  w01 = cza ? 1.f : w01;
      w10 = czb ? 1.f : w10;  w11 = czb ? 1.f : w11;
      la += w00 + w01;  lb += w10 + w11;
      ua.h[p] = pk2(w00, w01);
      ub.h[p] = pk2(w10, w11);
    }
    #pragma unroll
    for (int nt=0; nt<4; ++nt){
      f16x8 bv = ld8(whg + (size_t)(nt*16 + col)*NN + j8);
      acc[0][nt] = __builtin_amdgcn_mfma_f32_16x16x32_f16(ua.v, bv, acc[0][nt], 0, 0, 0);
      acc[1][nt] = __builtin_amdgcn_mfma_f32_16x16x32_f16(ub.v, bv, acc[1][nt], 0, 0, 0);
    }
  }
  // l: reduce over q (lanes col, col+16, col+32, col+48)
  la += __shfl_xor(la, 16, 64);  la += __shfl_xor(la, 32, 64);
  lb += __shfl_xor(lb, 16, 64);  lb += __shfl_xor(lb, 32, 64);
  if (q == 0){ lred[wv][col] = la; lred[wv][16+col] = lb; }
  // C partials to LDS
  #pragma unroll
  for (int mt=0; mt<2; ++mt)
    #pragma unroll
    for (int nt=0; nt<4; ++nt)
      #pragma unroll
      for (int reg=0; reg<4; ++reg)
        cred[wv][(mt*16 + q*4 + reg)*CP + nt*16 + col] = acc[mt][nt][reg];
  __syncthreads();
  // combine: thread t -> row=t>>3, d-group=(t&7)*8
  int row = tid >> 3, d0 = (tid & 7) * 8;
  float l = lred[0][row] + lred[1][row] + lred[2][row] + lred[3][row];
  bool cz = (cnt_in[b*NN + i0 + row] == 0);
  float il = cz ? (1.0f/(float)NN) : 1.0f/l;
  float4 s0 = {0,0,0,0}, s1 = {0,0,0,0};
  #pragma unroll
  for (int w=0; w<4; ++w){
    float4 v0 = *(const float4*)&cred[w][row*CP + d0];
    float4 v1 = *(const float4*)&cred[w][row*CP + d0 + 4];
    s0.x+=v0.x; s0.y+=v0.y; s0.z+=v0.z; s0.w+=v0.w;
    s1.x+=v1.x; s1.y+=v1.y; s1.z+=v1.z; s1.w+=v1.w;
  }
  float ov[8] = {s0.x,s0.y,s0.z,s0.w, s1.x,s1.y,s1.z,s1.w};
  #pragma unroll
  for (int dd=0; dd<8; ++dd){
    float v = ov[dd]*il;
    ov[dd] = v > 0.f ? v : expm1f(v);
  }
  float* dp = dst + ((size_t)(b*NN + i0 + row))*(NHEADS*NHID) + h*NHID + d0;
  *(float4*)dp       = float4{ov[0],ov[1],ov[2],ov[3]};
  *(float4*)(dp + 4) = float4{ov[4],ov[5],ov[6],ov[7]};
}

// ---------------- K3a: Wh2T(f16) = (h1 @ Wo)^T, f1ol/f2ol (log2e) -------
__global__ void __launch_bounds__(256) out_proj2(const float* __restrict__ h1,
        const float* __restrict__ Wo, const float* __restrict__ ao1, const float* __restrict__ ao2,
        _Float16* __restrict__ whT2, float* __restrict__ f1ol, float* __restrict__ f2ol){
  __shared__ __align__(16) float xs[64*65];
  __shared__ float red1[4][64];
  __shared__ float red2[4][64];
  int b = blockIdx.x >> 5;
  int i0 = (blockIdx.x & 31) * 64;
  int tid = threadIdx.x;
  int lane = tid & 63;
  int dbase = __builtin_amdgcn_readfirstlane(tid >> 6) * 8;
  float acc[8];
  #pragma unroll
  for (int dd=0; dd<8; ++dd) acc[dd] = 0.f;
  for (int kc=0; kc<4; ++kc){
    int kb = kc*64;
    __syncthreads();
    #pragma unroll
    for (int t=0; t<4; ++t){
      int row = t*16 + (tid>>4);
      int f4 = (tid&15)*4;
      float4 v = *(const float4*)(h1 + ((size_t)(b*NN + i0 + row))*256 + kb + f4);
      xs[row*65 + f4 + 0] = v.x;
      xs[row*65 + f4 + 1] = v.y;
      xs[row*65 + f4 + 2] = v.z;
      xs[row*65 + f4 + 3] = v.w;
    }
    __syncthreads();
    #pragma unroll 4
    for (int f=0; f<64; ++f){
      float xv = xs[lane*65 + f];
      const float* wr = Wo + (size_t)(kb+f)*NCLASS + dbase;
      #pragma unroll
      for (int dd=0; dd<8; ++dd) acc[dd] = fmaf(xv, wr[dd], acc[dd]);
    }
  }
  float p1 = 0.f, p2 = 0.f;
  #pragma unroll
  for (int dd=0; dd<8; ++dd){
    int d = dbase + dd;
    whT2[((size_t)b*NCLASS + d)*NN + i0 + lane] = (_Float16)acc[dd];
    p1 = fmaf(acc[dd], ao1[d], p1);
    p2 = fmaf(acc[dd], ao2[d], p2);
  }
  int wv = tid >> 6;
  red1[wv][lane] = p1;
  red2[wv][lane] = p2;
  __syncthreads();
  if (tid < 64){
    float s1 = red1[0][tid]+red1[1][tid]+red1[2][tid]+red1[3][tid];
    float s2 = red2[0][tid]+red2[1][tid]+red2[2][tid]+red2[3][tid];
    f1ol[(size_t)b*NN + i0 + tid] = s1 * LOG2E;
    f2ol[(size_t)b*NN + i0 + tid] = s2 * LOG2E;
  }
}

// ---------- K3b: layer-2 attention, GATHERED rows only, j-split x8 ------
__global__ void __launch_bounds__(256) attn_l2(
        const unsigned long long* __restrict__ bits,
        const _Float16* __restrict__ whT2,
        const float* __restrict__ f1ol, const float* __restrict__ f2ol,
        const int* __restrict__ cnt_in, const int* __restrict__ oh,
        float* __restrict__ pc, float* __restrict__ pl){
  const int JC = 128, PITCH = 132;
  __shared__ __align__(16) _Float16 whs[32*PITCH];
  __shared__ __align__(16) _Float16 wts[32*PITCH];
  int blk = blockIdx.x;
  int js = blk & 7, kt = (blk>>3) & 7, b = blk >> 6;
  int tid = threadIdx.x;
  int lane = tid & 63, wv = tid >> 6;
  int q = lane >> 4, col = lane & 15;
  int r = tid >> 3, jg = (tid & 7) * 16;
  int row_i = oh[b*KK1 + kt*32 + r];
  float f1r = f1ol[b*NN + row_i];
  bool czr = (cnt_in[b*NN + row_i] == 0);
  const unsigned short* mrow = (const unsigned short*)(bits + ((size_t)(b*NN + row_i))*(NN/64));
  const float* f2p = f2ol + (size_t)b*NN;
  const _Float16* whg = whT2 + (size_t)b*NCLASS*NN;
  float lacc = 0.f;
  f32x4 c0 = {0.f,0.f,0.f,0.f};
  int mt = wv & 1, nt = wv >> 1;
  for (int ii=0; ii<2; ++ii){
    int it = js*2 + ii;
    __syncthreads();
    #pragma unroll
    for (int dd=0; dd<2; ++dd){
      int d = (tid>>4) + dd*16;
      int j8 = (tid&15)*8;
      uint4 v = *(const uint4*)(whg + (size_t)d*NN + it*JC + j8);
      uint2* w2 = (uint2*)&whs[d*PITCH + j8];
      w2[0] = uint2{v.x, v.y};
      w2[1] = uint2{v.z, v.w};
    }
    {
      unsigned int m16 = mrow[it*8 + (tid&7)];
      const float* fp = f2p + it*JC + jg;
      float4 fa = *(const float4*)(fp);
      float4 fb = *(const float4*)(fp+4);
      float4 fc = *(const float4*)(fp+8);
      float4 fd = *(const float4*)(fp+12);
      float fv[16] = {fa.x,fa.y,fa.z,fa.w, fb.x,fb.y,fb.z,fb.w,
                      fc.x,fc.y,fc.z,fc.w, fd.x,fd.y,fd.z,fd.w};
      h16x2 wp[8];
      #pragma unroll
      for (int p=0; p<8; ++p){
        float s0 = f1r + fv[2*p];
        float s1 = f1r + fv[2*p+1];
        s0 = (m16 & (1u<<(2*p)))   ? s0 : -1e5f;
        s1 = (m16 & (1u<<(2*p+1))) ? s1 : -1e5f;
        float e0 = fmaxf(s0, ALPHA*s0);
        float e1 = fmaxf(s1, ALPHA*s1);
        float w0 = __builtin_amdgcn_exp2f(e0);
        float w1 = __builtin_amdgcn_exp2f(e1);
        lacc += w0 + w1;
        wp[p] = pk2(w0, w1);
      }
      if (__builtin_expect(czr, 0)){
        h16x2 one2 = {(_Float16)1.f, (_Float16)1.f};
        #pragma unroll
        for (int p=0; p<8; ++p) wp[p] = one2;
        lacc += 16.f;
      }
      uint2* wdst = (uint2*)&wts[r*PITCH + jg];
      const uint2* wsrc = (const uint2*)&wp[0];
      wdst[0]=wsrc[0]; wdst[1]=wsrc[1]; wdst[2]=wsrc[2]; wdst[3]=wsrc[3];
    }
    __syncthreads();
    #pragma unroll
    for (int ks=0; ks<4; ++ks){
      int kb = ks*32 + q*8;
      f16x8 a0 = ld8(&wts[(mt*16+col)*PITCH + kb]);
      f16x8 bv = ld8(&whs[(nt*16+col)*PITCH + kb]);
      c0 = __builtin_amdgcn_mfma_f32_16x16x32_f16(a0, bv, c0, 0, 0, 0);
    }
  }
  lacc += __shfl_xor(lacc, 1, 64);
  lacc += __shfl_xor(lacc, 2, 64);
  lacc += __shfl_xor(lacc, 4, 64);
  if ((tid & 7) == 0) pl[blk*32 + r] = lacc;
  int dloc = nt*16 + col;
  #pragma unroll
  for (int reg=0; reg<4; ++reg){
    int ir = mt*16 + q*4 + reg;
    pc[(size_t)blk*1024 + ir*32 + dloc] = c0[reg];
  }
}

// ---------------- K4: combine partials + ELU + MLP ----------------------
__global__ void __launch_bounds__(256) classify2(const float* __restrict__ pc,
        const float* __restrict__ pl,
        const float* __restrict__ W1, const float* __restrict__ b1,
        const float* __restrict__ pw, const float* __restrict__ W2, const float* __restrict__ b2,
        float* __restrict__ out){
  __shared__ float efs[4][32];
  int wv = threadIdx.x >> 6;
  int lane = threadIdx.x & 63;
  int row = blockIdx.x*4 + wv;        // 0..B*K1-1
  int b = row >> 8, k = row & 255;
  int kt = k >> 5, r = k & 31;
  int base = (b*8 + kt)*8;
  if (lane < 32){
    float s = 0.f, l = 0.f;
    #pragma unroll
    for (int js=0; js<8; ++js){
      s += pc[(size_t)(base+js)*1024 + r*32 + lane];
      l += pl[(base+js)*32 + r];
    }
    float v = s / l;
    v = v > 0.f ? v : expm1f(v);
    efs[wv][lane] = v;
  }
  __syncthreads();
  const float* ef = efs[wv];
  int c = lane & 31;
  float y = b1[c];
  #pragma unroll 8
  for (int kk=0; kk<32; ++kk) y += ef[kk] * W1[kk*32 + c];
  y = y > 0.f ? y : pw[c]*y;
  float o0 = y * W2[c*2+0];
  float o1 = y * W2[c*2+1];
  #pragma unroll
  for (int o=16;o>0;o>>=1){ o0 += __shfl_xor(o0,o,64); o1 += __shfl_xor(o1,o,64); }
  if (lane==0){ out[row*2+0] = o0 + b2[0]; out[row*2+1] = o1 + b2[1]; }
}

extern "C" void kernel_launch(void* const* d_in, const int* in_sizes, int n_in,
                              void* d_out, int out_size, void* d_ws, size_t ws_size,
                              hipStream_t stream) {
  const float* x    = (const float*)d_in[0];
  const int*   adj  = (const int*)  d_in[1];
  const int*   oh   = (const int*)  d_in[2];
  const float* W    = (const float*)d_in[3];
  const float* a1   = (const float*)d_in[4];
  const float* a2   = (const float*)d_in[5];
  const float* Wo   = (const float*)d_in[6];
  const float* ao1  = (const float*)d_in[7];
  const float* ao2  = (const float*)d_in[8];
  const float* W1   = (const float*)d_in[9];
  const float* b1   = (const float*)d_in[10];
  const float* pw   = (const float*)d_in[11];
  const float* W2   = (const float*)d_in[12];
  const float* b2   = (const float*)d_in[13];
  float* out = (float*)d_out;

  char* base = (char*)d_ws;
  size_t off = 0;
  auto alloc = [&](size_t bytes)->char*{
    char* p = base + off;
    off = (off + bytes + 255) & ~(size_t)255;
    return p;
  };
  unsigned long long* adjbits = (unsigned long long*)alloc((size_t)BB*NN*(NN/64)*8); // 2 MB
  int*   cnt1 = (int*)  alloc((size_t)BB*NN*4);
  _Float16* WhT  = (_Float16*)alloc((size_t)BB*NHEADS*NHID*NN*2);  // 4 MB, [bh][d][i]
  float* f1l  = (float*)alloc((size_t)BB*NHEADS*NN*4);
  float* f2l  = (float*)alloc((size_t)BB*NHEADS*NN*4);
  float* h1   = (float*)alloc((size_t)BB*NN*(NHEADS*NHID)*4);      // 8 MB
  _Float16* WhT2 = (_Float16*)alloc((size_t)BB*NCLASS*NN*2);       // 512 KB, [b][d][i]
  float* f1ol = (float*)alloc((size_t)BB*NN*4);
  float* f2ol = (float*)alloc((size_t)BB*NN*4);
  float* pc   = (float*)alloc((size_t)256*1024*4);                 // 1 MB partial c
  float* pl   = (float*)alloc((size_t)256*32*4);                   // partial l

  pack_adj<<<BB*NN, 256, 0, stream>>>(adj, adjbits, cnt1);
  wh_proj2<<<BB*NHEADS*(NN/64), 256, 0, stream>>>(x, W, a1, a2, WhT, f1l, f2l);
  attn_l1<<<BB*NHEADS*(NN/32), 256, 0, stream>>>(adjbits, WhT, f1l, f2l, cnt1, h1);
  out_proj2<<<BB*(NN/64), 256, 0, stream>>>(h1, Wo, ao1, ao2, WhT2, f1ol, f2ol);
  attn_l2<<<BB*8*8, 256, 0, stream>>>(adjbits, WhT2, f1ol, f2ol, cnt1, oh, pc, pl);
  classify2<<<(BB*KK1)/4, 256, 0, stream>>>(pc, pl, W1, b1, pw, W2, b2, out);
}

// Round 7
// 235.025 us; speedup vs baseline: 1.0647x; 1.0647x over previous
//
#include <hip/hip_runtime.h>
#include <hip/hip_bf16.h>
#include <stdint.h>
#include <math.h>

#define BB 4
#define NN 2048
#define NFEAT 256
#define NHID 64
#define NHEADS 4
#define NCLASS 32
#define KK1 256
#define ALPHA 0.2f
#define LOG2E 1.4426950408889634f

typedef _Float16 f16x8 __attribute__((ext_vector_type(8)));
typedef _Float16 f16x4 __attribute__((ext_vector_type(4)));
typedef _Float16 h16x2 __attribute__((ext_vector_type(2)));
typedef float f32x4 __attribute__((ext_vector_type(4)));

__device__ __forceinline__ f16x8 ld8(const _Float16* p){
  f16x8 r;
  *(f16x4*)&r = *(const f16x4*)p;
  *((f16x4*)&r + 1) = *(const f16x4*)(p + 4);
  return r;
}

__device__ __forceinline__ h16x2 pk2(float a, float b){
  auto v = __builtin_amdgcn_cvt_pkrtz(a, b);   // __fp16 x2
  h16x2 r;
  __builtin_memcpy(&r, &v, sizeof(r));
  return r;
}

// ---------------- K0: pack adj int32 -> bitmask + per-row count ---------
__global__ void __launch_bounds__(256) pack_adj(const int* __restrict__ adj,
                                                unsigned long long* __restrict__ bits,
                                                int* __restrict__ cnt){
  __shared__ int csum[4];
  int row = blockIdx.x;                       // b*N + i
  const int* arow = adj + (size_t)row * NN;
  int lane = threadIdx.x & 63, wv = threadIdx.x >> 6;
  int c = 0;
  #pragma unroll
  for (int it=0; it<NN/256; ++it){
    int j = it*256 + threadIdx.x;
    unsigned long long m = __ballot(arow[j] > 0);
    if (lane==0){ bits[(size_t)row*(NN/64) + it*4 + wv] = m; c += __popcll(m); }
  }
  if (lane==0) csum[wv] = c;
  __syncthreads();
  if (threadIdx.x==0) cnt[row] = csum[0]+csum[1]+csum[2]+csum[3];
}

// ---------------- K1: WhT(f16) = (x @ W)^T per head, f1l/f2l (log2e) ----
__global__ void __launch_bounds__(256) wh_proj2(const float* __restrict__ x,
        const float* __restrict__ W, const float* __restrict__ a1, const float* __restrict__ a2,
        _Float16* __restrict__ whT, float* __restrict__ f1l, float* __restrict__ f2l){
  __shared__ __align__(16) float xs[64*65];
  __shared__ float red1[4][64];
  __shared__ float red2[4][64];
  int bh = blockIdx.x >> 5;
  int i0 = (blockIdx.x & 31) * 64;
  int b = bh >> 2, h = bh & 3;
  int tid = threadIdx.x;
  int lane = tid & 63;
  int dbase = __builtin_amdgcn_readfirstlane(tid >> 6) * 16;
  float acc[16];
  #pragma unroll
  for (int dd=0; dd<16; ++dd) acc[dd] = 0.f;
  for (int kc=0; kc<4; ++kc){
    int kb = kc*64;
    __syncthreads();
    #pragma unroll
    for (int t=0; t<4; ++t){
      int row = t*16 + (tid>>4);
      int f4 = (tid&15)*4;
      float4 v = *(const float4*)(x + ((size_t)(b*NN + i0 + row))*NFEAT + kb + f4);
      xs[row*65 + f4 + 0] = v.x;
      xs[row*65 + f4 + 1] = v.y;
      xs[row*65 + f4 + 2] = v.z;
      xs[row*65 + f4 + 3] = v.w;
    }
    __syncthreads();
    const float* Wb = W + (size_t)h*NFEAT*NHID + (size_t)kb*NHID + dbase;
    #pragma unroll 4
    for (int f=0; f<64; ++f){
      float xv = xs[lane*65 + f];
      const float* wr = Wb + f*NHID;
      #pragma unroll
      for (int dd=0; dd<16; ++dd) acc[dd] = fmaf(xv, wr[dd], acc[dd]);
    }
  }
  float p1 = 0.f, p2 = 0.f;
  #pragma unroll
  for (int dd=0; dd<16; ++dd){
    int d = dbase + dd;
    whT[((size_t)bh*NHID + d)*NN + i0 + lane] = (_Float16)acc[dd];
    p1 = fmaf(acc[dd], a1[h*NHID + d], p1);
    p2 = fmaf(acc[dd], a2[h*NHID + d], p2);
  }
  int wv = tid >> 6;
  red1[wv][lane] = p1;
  red2[wv][lane] = p2;
  __syncthreads();
  if (tid < 64){
    float s1 = red1[0][tid]+red1[1][tid]+red1[2][tid]+red1[3][tid];
    float s2 = red2[0][tid]+red2[1][tid]+red2[2][tid]+red2[3][tid];
    f1l[(size_t)bh*NN + i0 + tid] = s1 * LOG2E;
    f2l[(size_t)bh*NN + i0 + tid] = s2 * LOG2E;
  }
}

// ---------- K2: h1 = elu(softmax(e) @ Wh), A-in-registers, B in LDS -----
// grid = bh(16) x tile(32); block 256 = 4 waves. Wave w owns m-rows
// i0+w*16..+16 over ALL j (no K-split => no cross-wave C reduce).
// Lane (q,col) computes weights for row col directly in MFMA A-layout.
// B chunk (64d x 128j f16) staged in LDS pitch 136 (16B-aligned b128 ops).
__global__ void __launch_bounds__(256) attn_l1(
        const unsigned long long* __restrict__ bits,
        const _Float16* __restrict__ whT,
        const float* __restrict__ f1l, const float* __restrict__ f2l,
        const int* __restrict__ cnt_in,
        float* __restrict__ dst){
  const int PITCH = 136;
  __shared__ __align__(16) _Float16 whs[64*PITCH];   // 17.4 KB
  __shared__ float ils[4][16];
  int tile = blockIdx.x & 31;
  int bh = blockIdx.x >> 5;
  int b = bh >> 2, h = bh & 3;
  int i0 = tile*64;
  int tid = threadIdx.x;
  int lane = tid & 63, w = tid >> 6;
  int q = lane >> 4, col = lane & 15;
  int mrow = i0 + w*16 + col;
  float f1r = f1l[(size_t)bh*NN + mrow];
  bool cz = (cnt_in[b*NN + mrow] == 0);
  const unsigned int* mr = (const unsigned int*)(bits + ((size_t)(b*NN + mrow))*(NN/64));
  const float* f2p = f2l + (size_t)bh*NN;
  const _Float16* whg = whT + (size_t)bh*NHID*NN;
  // staging coords: thread -> (d row, 64B quarter)
  int sd = tid >> 2, sq = tid & 3;
  const _Float16* sg = whg + (size_t)sd*NN + sq*32;
  _Float16* sl = whs + sd*PITCH + sq*32;
  float lacc = 0.f;
  f32x4 acc[4];
  #pragma unroll
  for (int nt=0; nt<4; ++nt) acc[nt] = f32x4{0.f,0.f,0.f,0.f};

  for (int it=0; it<16; ++it){
    __syncthreads();
    {
      uint4 t0 = *(const uint4*)(sg + it*128);
      uint4 t1 = *(const uint4*)(sg + it*128 + 8);
      uint4 t2 = *(const uint4*)(sg + it*128 + 16);
      uint4 t3 = *(const uint4*)(sg + it*128 + 24);
      *(uint4*)(sl)      = t0;
      *(uint4*)(sl + 8)  = t1;
      *(uint4*)(sl + 16) = t2;
      *(uint4*)(sl + 24) = t3;
    }
    uint4 mw4 = *(const uint4*)(mr + it*4);    // masks for 4 ks steps
    __syncthreads();
    #pragma unroll
    for (int ks=0; ks<4; ++ks){
      unsigned int mw = ((const unsigned int*)&mw4)[ks];
      int j8 = it*128 + ks*32 + q*8;
      float4 fa = *(const float4*)(f2p + j8);
      float4 fb = *(const float4*)(f2p + j8 + 4);
      float fv[8] = {fa.x,fa.y,fa.z,fa.w, fb.x,fb.y,fb.z,fb.w};
      union { f16x8 v; h16x2 h[4]; } ua;
      #pragma unroll
      for (int p=0; p<4; ++p){
        unsigned sh = q*8 + 2*p;
        float s0 = f1r + fv[2*p];
        float s1 = f1r + fv[2*p+1];
        s0 = ((mw>>sh)&1u)     ? s0 : -1e5f;
        s1 = ((mw>>(sh+1))&1u) ? s1 : -1e5f;
        float w0 = __builtin_amdgcn_exp2f(fmaxf(s0, ALPHA*s0));
        float w1 = __builtin_amdgcn_exp2f(fmaxf(s1, ALPHA*s1));
        w0 = cz ? 1.f : w0;
        w1 = cz ? 1.f : w1;
        lacc += w0 + w1;
        ua.h[p] = pk2(w0, w1);
      }
      #pragma unroll
      for (int nt=0; nt<4; ++nt){
        f16x8 bv = ld8(&whs[(nt*16 + col)*PITCH + ks*32 + q*8]);
        acc[nt] = __builtin_amdgcn_mfma_f32_16x16x32_f16(ua.v, bv, acc[nt], 0, 0, 0);
      }
    }
  }
  // l: reduce over q (lanes col, col+16, col+32, col+48); cz rows sum to N
  lacc += __shfl_xor(lacc, 16, 64);
  lacc += __shfl_xor(lacc, 32, 64);
  if (q == 0) ils[w][col] = 1.0f / lacc;
  __syncthreads();
  // epilogue: D[m=q*4+reg][n=col] per nt; scale, ELU, store
  #pragma unroll
  for (int reg=0; reg<4; ++reg){
    int ir = q*4 + reg;
    float ilv = ils[w][ir];
    float* dp = dst + ((size_t)(b*NN + i0 + w*16 + ir))*(NHEADS*NHID) + h*NHID + col;
    #pragma unroll
    for (int nt=0; nt<4; ++nt){
      float v = acc[nt][reg] * ilv;
      v = v > 0.f ? v : expm1f(v);
      dp[nt*16] = v;
    }
  }
}

// ---------------- K3a: Wh2T(f16) = (h1 @ Wo)^T, f1ol/f2ol (log2e) -------
__global__ void __launch_bounds__(256) out_proj2(const float* __restrict__ h1,
        const float* __restrict__ Wo, const float* __restrict__ ao1, const float* __restrict__ ao2,
        _Float16* __restrict__ whT2, float* __restrict__ f1ol, float* __restrict__ f2ol){
  __shared__ __align__(16) float xs[64*65];
  __shared__ float red1[4][64];
  __shared__ float red2[4][64];
  int b = blockIdx.x >> 5;
  int i0 = (blockIdx.x & 31) * 64;
  int tid = threadIdx.x;
  int lane = tid & 63;
  int dbase = __builtin_amdgcn_readfirstlane(tid >> 6) * 8;
  float acc[8];
  #pragma unroll
  for (int dd=0; dd<8; ++dd) acc[dd] = 0.f;
  for (int kc=0; kc<4; ++kc){
    int kb = kc*64;
    __syncthreads();
    #pragma unroll
    for (int t=0; t<4; ++t){
      int row = t*16 + (tid>>4);
      int f4 = (tid&15)*4;
      float4 v = *(const float4*)(h1 + ((size_t)(b*NN + i0 + row))*256 + kb + f4);
      xs[row*65 + f4 + 0] = v.x;
      xs[row*65 + f4 + 1] = v.y;
      xs[row*65 + f4 + 2] = v.z;
      xs[row*65 + f4 + 3] = v.w;
    }
    __syncthreads();
    #pragma unroll 4
    for (int f=0; f<64; ++f){
      float xv = xs[lane*65 + f];
      const float* wr = Wo + (size_t)(kb+f)*NCLASS + dbase;
      #pragma unroll
      for (int dd=0; dd<8; ++dd) acc[dd] = fmaf(xv, wr[dd], acc[dd]);
    }
  }
  float p1 = 0.f, p2 = 0.f;
  #pragma unroll
  for (int dd=0; dd<8; ++dd){
    int d = dbase + dd;
    whT2[((size_t)b*NCLASS + d)*NN + i0 + lane] = (_Float16)acc[dd];
    p1 = fmaf(acc[dd], ao1[d], p1);
    p2 = fmaf(acc[dd], ao2[d], p2);
  }
  int wv = tid >> 6;
  red1[wv][lane] = p1;
  red2[wv][lane] = p2;
  __syncthreads();
  if (tid < 64){
    float s1 = red1[0][tid]+red1[1][tid]+red1[2][tid]+red1[3][tid];
    float s2 = red2[0][tid]+red2[1][tid]+red2[2][tid]+red2[3][tid];
    f1ol[(size_t)b*NN + i0 + tid] = s1 * LOG2E;
    f2ol[(size_t)b*NN + i0 + tid] = s2 * LOG2E;
  }
}

// ---------- K3b: layer-2 attention, GATHERED rows only, j-split x8 ------
__global__ void __launch_bounds__(256) attn_l2(
        const unsigned long long* __restrict__ bits,
        const _Float16* __restrict__ whT2,
        const float* __restrict__ f1ol, const float* __restrict__ f2ol,
        const int* __restrict__ cnt_in, const int* __restrict__ oh,
        float* __restrict__ pc, float* __restrict__ pl){
  const int JC = 128, PITCH = 132;
  __shared__ __align__(16) _Float16 whs[32*PITCH];
  __shared__ __align__(16) _Float16 wts[32*PITCH];
  int blk = blockIdx.x;
  int js = blk & 7, kt = (blk>>3) & 7, b = blk >> 6;
  int tid = threadIdx.x;
  int lane = tid & 63, wv = tid >> 6;
  int q = lane >> 4, col = lane & 15;
  int r = tid >> 3, jg = (tid & 7) * 16;
  int row_i = oh[b*KK1 + kt*32 + r];
  float f1r = f1ol[b*NN + row_i];
  bool czr = (cnt_in[b*NN + row_i] == 0);
  const unsigned short* mrow = (const unsigned short*)(bits + ((size_t)(b*NN + row_i))*(NN/64));
  const float* f2p = f2ol + (size_t)b*NN;
  const _Float16* whg = whT2 + (size_t)b*NCLASS*NN;
  float lacc = 0.f;
  f32x4 c0 = {0.f,0.f,0.f,0.f};
  int mt = wv & 1, nt = wv >> 1;
  for (int ii=0; ii<2; ++ii){
    int it = js*2 + ii;
    __syncthreads();
    #pragma unroll
    for (int dd=0; dd<2; ++dd){
      int d = (tid>>4) + dd*16;
      int j8 = (tid&15)*8;
      uint4 v = *(const uint4*)(whg + (size_t)d*NN + it*JC + j8);
      uint2* w2 = (uint2*)&whs[d*PITCH + j8];
      w2[0] = uint2{v.x, v.y};
      w2[1] = uint2{v.z, v.w};
    }
    {
      unsigned int m16 = mrow[it*8 + (tid&7)];
      const float* fp = f2p + it*JC + jg;
      float4 fa = *(const float4*)(fp);
      float4 fb = *(const float4*)(fp+4);
      float4 fc = *(const float4*)(fp+8);
      float4 fd = *(const float4*)(fp+12);
      float fv[16] = {fa.x,fa.y,fa.z,fa.w, fb.x,fb.y,fb.z,fb.w,
                      fc.x,fc.y,fc.z,fc.w, fd.x,fd.y,fd.z,fd.w};
      h16x2 wp[8];
      #pragma unroll
      for (int p=0; p<8; ++p){
        float s0 = f1r + fv[2*p];
        float s1 = f1r + fv[2*p+1];
        s0 = (m16 & (1u<<(2*p)))   ? s0 : -1e5f;
        s1 = (m16 & (1u<<(2*p+1))) ? s1 : -1e5f;
        float e0 = fmaxf(s0, ALPHA*s0);
        float e1 = fmaxf(s1, ALPHA*s1);
        float w0 = __builtin_amdgcn_exp2f(e0);
        float w1 = __builtin_amdgcn_exp2f(e1);
        lacc += w0 + w1;
        wp[p] = pk2(w0, w1);
      }
      if (__builtin_expect(czr, 0)){
        h16x2 one2 = {(_Float16)1.f, (_Float16)1.f};
        #pragma unroll
        for (int p=0; p<8; ++p) wp[p] = one2;
        lacc += 16.f;
      }
      uint2* wdst = (uint2*)&wts[r*PITCH + jg];
      const uint2* wsrc = (const uint2*)&wp[0];
      wdst[0]=wsrc[0]; wdst[1]=wsrc[1]; wdst[2]=wsrc[2]; wdst[3]=wsrc[3];
    }
    __syncthreads();
    #pragma unroll
    for (int ks=0; ks<4; ++ks){
      int kb = ks*32 + q*8;
      f16x8 a0 = ld8(&wts[(mt*16+col)*PITCH + kb]);
      f16x8 bv = ld8(&whs[(nt*16+col)*PITCH + kb]);
      c0 = __builtin_amdgcn_mfma_f32_16x16x32_f16(a0, bv, c0, 0, 0, 0);
    }
  }
  lacc += __shfl_xor(lacc, 1, 64);
  lacc += __shfl_xor(lacc, 2, 64);
  lacc += __shfl_xor(lacc, 4, 64);
  if ((tid & 7) == 0) pl[blk*32 + r] = lacc;
  int dloc = nt*16 + col;
  #pragma unroll
  for (int reg=0; reg<4; ++reg){
    int ir = mt*16 + q*4 + reg;
    pc[(size_t)blk*1024 + ir*32 + dloc] = c0[reg];
  }
}

// ---------------- K4: combine partials + ELU + MLP ----------------------
__global__ void __launch_bounds__(256) classify2(const float* __restrict__ pc,
        const float* __restrict__ pl,
        const float* __restrict__ W1, const float* __restrict__ b1,
        const float* __restrict__ pw, const float* __restrict__ W2, const float* __restrict__ b2,
        float* __restrict__ out){
  __shared__ float efs[4][32];
  int wv = threadIdx.x >> 6;
  int lane = threadIdx.x & 63;
  int row = blockIdx.x*4 + wv;        // 0..B*K1-1
  int b = row >> 8, k = row & 255;
  int kt = k >> 5, r = k & 31;
  int base = (b*8 + kt)*8;
  if (lane < 32){
    float s = 0.f, l = 0.f;
    #pragma unroll
    for (int js=0; js<8; ++js){
      s += pc[(size_t)(base+js)*1024 + r*32 + lane];
      l += pl[(base+js)*32 + r];
    }
    float v = s / l;
    v = v > 0.f ? v : expm1f(v);
    efs[wv][lane] = v;
  }
  __syncthreads();
  const float* ef = efs[wv];
  int c = lane & 31;
  float y = b1[c];
  #pragma unroll 8
  for (int kk=0; kk<32; ++kk) y += ef[kk] * W1[kk*32 + c];
  y = y > 0.f ? y : pw[c]*y;
  float o0 = y * W2[c*2+0];
  float o1 = y * W2[c*2+1];
  #pragma unroll
  for (int o=16;o>0;o>>=1){ o0 += __shfl_xor(o0,o,64); o1 += __shfl_xor(o1,o,64); }
  if (lane==0){ out[row*2+0] = o0 + b2[0]; out[row*2+1] = o1 + b2[1]; }
}

extern "C" void kernel_launch(void* const* d_in, const int* in_sizes, int n_in,
                              void* d_out, int out_size, void* d_ws, size_t ws_size,
                              hipStream_t stream) {
  const float* x    = (const float*)d_in[0];
  const int*   adj  = (const int*)  d_in[1];
  const int*   oh   = (const int*)  d_in[2];
  const float* W    = (const float*)d_in[3];
  const float* a1   = (const float*)d_in[4];
  const float* a2   = (const float*)d_in[5];
  const float* Wo   = (const float*)d_in[6];
  const float* ao1  = (const float*)d_in[7];
  const float* ao2  = (const float*)d_in[8];
  const float* W1   = (const float*)d_in[9];
  const float* b1   = (const float*)d_in[10];
  const float* pw   = (const float*)d_in[11];
  const float* W2   = (const float*)d_in[12];
  const float* b2   = (const float*)d_in[13];
  float* out = (float*)d_out;

  char* base = (char*)d_ws;
  size_t off = 0;
  auto alloc = [&](size_t bytes)->char*{
    char* p = base + off;
    off = (off + bytes + 255) & ~(size_t)255;
    return p;
  };
  unsigned long long* adjbits = (unsigned long long*)alloc((size_t)BB*NN*(NN/64)*8); // 2 MB
  int*   cnt1 = (int*)  alloc((size_t)BB*NN*4);
  _Float16* WhT  = (_Float16*)alloc((size_t)BB*NHEADS*NHID*NN*2);  // 4 MB, [bh][d][i]
  float* f1l  = (float*)alloc((size_t)BB*NHEADS*NN*4);
  float* f2l  = (float*)alloc((size_t)BB*NHEADS*NN*4);
  float* h1   = (float*)alloc((size_t)BB*NN*(NHEADS*NHID)*4);      // 8 MB
  _Float16* WhT2 = (_Float16*)alloc((size_t)BB*NCLASS*NN*2);       // 512 KB, [b][d][i]
  float* f1ol = (float*)alloc((size_t)BB*NN*4);
  float* f2ol = (float*)alloc((size_t)BB*NN*4);
  float* pc   = (float*)alloc((size_t)256*1024*4);                 // 1 MB partial c
  float* pl   = (float*)alloc((size_t)256*32*4);                   // partial l

  pack_adj<<<BB*NN, 256, 0, stream>>>(adj, adjbits, cnt1);
  wh_proj2<<<BB*NHEADS*(NN/64), 256, 0, stream>>>(x, W, a1, a2, WhT, f1l, f2l);
  attn_l1<<<BB*NHEADS*(NN/64), 256, 0, stream>>>(adjbits, WhT, f1l, f2l, cnt1, h1);
  out_proj2<<<BB*(NN/64), 256, 0, stream>>>(h1, Wo, ao1, ao2, WhT2, f1ol, f2ol);
  attn_l2<<<BB*8*8, 256, 0, stream>>>(adjbits, WhT2, f1ol, f2ol, cnt1, oh, pc, pl);
  classify2<<<(BB*KK1)/4, 256, 0, stream>>>(pc, pl, W1, b1, pw, W2, b2, out);
}